// Round 2
// baseline (63.839 us; speedup 1.0000x reference)
//
#include <hip/hip_runtime.h>

// PARAFAC CP-rank-16 query kernel.
// U,V,W: [R=16][D=400] row-major f32. index: [N][3] int32. out: [N] f32.
// out[n] = sum_r U[r,i]*V[r,j]*W[r,k]

#define RANK 16
#define DIM  400
#define PER  (RANK * DIM)   // 6400 floats per factor

// Transpose all three factors from [R][D] to [D][R] into ws.
// ws layout: Ut at ws[0], Vt at ws[6400], Wt at ws[12800]; Ut[i*16 + r] = U[r*400 + i].
__global__ void cp_transpose_factors(const float* __restrict__ U,
                                     const float* __restrict__ V,
                                     const float* __restrict__ W,
                                     float* __restrict__ ws) {
    int tid = blockIdx.x * blockDim.x + threadIdx.x;
    if (tid >= 3 * PER) return;
    int f   = tid / PER;
    int rem = tid - f * PER;
    int r   = rem / DIM;
    int i   = rem - r * DIM;
    const float* src = (f == 0) ? U : (f == 1) ? V : W;
    ws[f * PER + i * RANK + r] = src[rem];
}

// Main gather: transposed factors, contiguous 64B per factor per query.
__global__ void cp_gather(const float* __restrict__ ws,
                          const int* __restrict__ idx,
                          float* __restrict__ out, int n) {
    int t = blockIdx.x * blockDim.x + threadIdx.x;
    if (t >= n) return;
    int i = idx[3 * t + 0];
    int j = idx[3 * t + 1];
    int k = idx[3 * t + 2];
    const float4* Ut = (const float4*)(ws);
    const float4* Vt = (const float4*)(ws + PER);
    const float4* Wt = (const float4*)(ws + 2 * PER);
    float acc = 0.0f;
#pragma unroll
    for (int q = 0; q < 4; ++q) {
        float4 u = Ut[i * 4 + q];
        float4 v = Vt[j * 4 + q];
        float4 w = Wt[k * 4 + q];
        acc = fmaf(u.x, v.x * w.x, acc);
        acc = fmaf(u.y, v.y * w.y, acc);
        acc = fmaf(u.z, v.z * w.z, acc);
        acc = fmaf(u.w, v.w * w.w, acc);
    }
    out[t] = acc;
}

// Fallback (no workspace): direct strided gather from native [R][D] layout.
__global__ void cp_gather_direct(const float* __restrict__ U,
                                 const float* __restrict__ V,
                                 const float* __restrict__ W,
                                 const int* __restrict__ idx,
                                 float* __restrict__ out, int n) {
    int t = blockIdx.x * blockDim.x + threadIdx.x;
    if (t >= n) return;
    int i = idx[3 * t + 0];
    int j = idx[3 * t + 1];
    int k = idx[3 * t + 2];
    float acc = 0.0f;
#pragma unroll
    for (int r = 0; r < RANK; ++r) {
        acc = fmaf(U[r * DIM + i], V[r * DIM + j] * W[r * DIM + k], acc);
    }
    out[t] = acc;
}

extern "C" void kernel_launch(void* const* d_in, const int* in_sizes, int n_in,
                              void* d_out, int out_size, void* d_ws, size_t ws_size,
                              hipStream_t stream) {
    const float* U   = (const float*)d_in[0];
    const float* V   = (const float*)d_in[1];
    const float* W   = (const float*)d_in[2];
    const int*   idx = (const int*)d_in[3];
    float*       out = (float*)d_out;
    const int n = out_size;  // 100000 queries

    if (ws_size >= (size_t)(3 * PER) * sizeof(float)) {
        float* ws = (float*)d_ws;
        {
            int total = 3 * PER;
            int blk = 256;
            cp_transpose_factors<<<(total + blk - 1) / blk, blk, 0, stream>>>(U, V, W, ws);
        }
        {
            int blk = 256;
            cp_gather<<<(n + blk - 1) / blk, blk, 0, stream>>>(ws, idx, out, n);
        }
    } else {
        int blk = 256;
        cp_gather_direct<<<(n + blk - 1) / blk, blk, 0, stream>>>(U, V, W, idx, out, n);
    }
}

// Round 3
// 61.508 us; speedup vs baseline: 1.0379x; 1.0379x over previous
//
#include <hip/hip_runtime.h>

// PARAFAC CP-rank-16 query kernel, fused single-launch version.
// U,V,W: [R=16][D=400] row-major f32. index: [N][3] int32. out: [N] f32.
// out[n] = sum_r U[r,i]*V[r,j]*W[r,k]
//
// Strategy: each block copies all three factor tables (76.8 KB) into LDS with
// coalesced float4 loads (native layout — LDS random access needs no
// transpose), then each thread answers one query entirely from LDS.
// One kernel launch total; factors are L2-resident for the staging reads.

#define RANK 16
#define DIM  400
#define PER  (RANK * DIM)     // 6400 floats per factor
#define PER4 (PER / 4)        // 1600 float4 per factor
#define BLOCK 512
#define QPB   512             // queries per block (1 per thread)

__global__ __launch_bounds__(BLOCK)
void cp_fused(const float* __restrict__ U,
              const float* __restrict__ V,
              const float* __restrict__ W,
              const int* __restrict__ idx,
              float* __restrict__ out, int n) {
    __shared__ float lds[3 * PER];   // 76.8 KB -> 2 blocks/CU max on gfx950

    // Stage all three factors, vectorized, zero bank conflicts on write.
    {
        const float4* U4 = (const float4*)U;
        const float4* V4 = (const float4*)V;
        const float4* W4 = (const float4*)W;
        float4* L4 = (float4*)lds;
        for (int c = threadIdx.x; c < PER4; c += BLOCK) {
            L4[c]            = U4[c];
            L4[c + PER4]     = V4[c];
            L4[c + 2 * PER4] = W4[c];
        }
    }
    __syncthreads();

    int t = blockIdx.x * QPB + threadIdx.x;
    if (t >= n) return;

    int i = idx[3 * t + 0];
    int j = idx[3 * t + 1];
    int k = idx[3 * t + 2];

    const float* Ul = lds;
    const float* Vl = lds + PER;
    const float* Wl = lds + 2 * PER;

    float acc = 0.0f;
#pragma unroll
    for (int r = 0; r < RANK; ++r) {
        acc = fmaf(Ul[r * DIM + i], Vl[r * DIM + j] * Wl[r * DIM + k], acc);
    }
    out[t] = acc;
}

extern "C" void kernel_launch(void* const* d_in, const int* in_sizes, int n_in,
                              void* d_out, int out_size, void* d_ws, size_t ws_size,
                              hipStream_t stream) {
    const float* U   = (const float*)d_in[0];
    const float* V   = (const float*)d_in[1];
    const float* W   = (const float*)d_in[2];
    const int*   idx = (const int*)d_in[3];
    float*       out = (float*)d_out;
    const int n = out_size;  // 100000 queries

    int grid = (n + QPB - 1) / QPB;  // 196 blocks
    cp_fused<<<grid, BLOCK, 0, stream>>>(U, V, W, idx, out, n);
}